// Round 4
// baseline (2579.212 us; speedup 1.0000x reference)
//
#include <hip/hip_runtime.h>
#include <stdint.h>
#include <stddef.h>

#define N_ 8
#define T_ 512
#define C_ 1024
#define H_ 256
#define V_ 32000
#define CW 32      // columns per chunk

// workspace byte offsets
#define OFF_START   0u
#define OFF_LSE     4096u
#define OFF_EVP     8192u        // 8 f32 per-seq evidence
#define OFF_EA      16384u       // 2*8*1024 tagged u32 = 64KB (memset 0 each launch)
#define OFF_FT      81920u       // 1024*256 f32 = 1MB
#define OFF_P       1130496u     // 1024*1024 f32 = 4MB
#define OFF_PART    5324800u     // 1024*16 f32 partials
#define OFF_EEXP    5849088u     // 4096*1024 f32 = 16MB

typedef __attribute__((ext_vector_type(8))) short short8;
typedef __attribute__((ext_vector_type(4))) float floatx4;

__device__ __forceinline__ float dot4(float4 a, float4 b) {
  return a.x*b.x + a.y*b.y + a.z*b.z + a.w*b.w;
}

__device__ __forceinline__ unsigned short f2bf(float f) {
  unsigned u = __float_as_uint(f);
  unsigned r = u + 0x7fffu + ((u >> 16) & 1u);   // round-to-nearest-even
  return (unsigned short)(r >> 16);
}

__device__ __forceinline__ unsigned pk_bf2(float x, float y) {
  return ((unsigned)f2bf(y) << 16) | (unsigned)f2bf(x);
}

__device__ __forceinline__ short8 pack8(float4 a, float4 b) {
  union { short8 s; unsigned u[4]; } r;
  r.u[0] = pk_bf2(a.x, a.y);
  r.u[1] = pk_bf2(a.z, a.w);
  r.u[2] = pk_bf2(b.x, b.y);
  r.u[3] = pk_bf2(b.z, b.w);
  return r.s;
}

// ---------------------------------------------------------------- K1: start distribution
__global__ __launch_bounds__(256) void k_start(
    const float* __restrict__ se, const float* __restrict__ lw, const float* __restrict__ lb,
    const float* __restrict__ W1, const float* __restrict__ b1,
    const float* __restrict__ W2, const float* __restrict__ b2,
    const float* __restrict__ nse, float* __restrict__ out_start)
{
  __shared__ float xs[H_], fx[H_], h1[H_];
  __shared__ float lg[C_];
  __shared__ float redk[4];
  int tid = threadIdx.x;
  xs[tid] = se[tid];
  __syncthreads();
  {
    float acc = lb[tid];
    const float4* wr = (const float4*)(lw + (size_t)tid*H_);
    for (int k = 0; k < H_/4; ++k) acc += dot4(wr[k], *(const float4*)&xs[k*4]);
    fx[tid] = acc;
  }
  __syncthreads();
  for (int L = 0; L < 2; ++L) {
    {
      float acc = b1[L*H_ + tid];
      const float4* wr = (const float4*)(W1 + (size_t)(L*H_ + tid)*H_);
      for (int k = 0; k < H_/4; ++k) acc += dot4(wr[k], *(const float4*)&fx[k*4]);
      h1[tid] = fmaxf(acc, 0.f);
    }
    __syncthreads();
    {
      float acc = b2[L*H_ + tid];
      const float4* wr = (const float4*)(W2 + (size_t)(L*H_ + tid)*H_);
      for (int k = 0; k < H_/4; ++k) acc += dot4(wr[k], *(const float4*)&h1[k*4]);
      fx[tid] += fmaxf(acc, 0.f);
    }
    __syncthreads();
  }
  float lmax = -1e30f;
  for (int r = 0; r < 4; ++r) {
    int cc = tid + r*256;
    float acc = 0.f;
    const float4* er = (const float4*)(nse + (size_t)cc*H_);
    for (int k = 0; k < H_/4; ++k) acc += dot4(er[k], *(const float4*)&fx[k*4]);
    lg[cc] = acc;
    lmax = fmaxf(lmax, acc);
  }
  for (int m = 32; m; m >>= 1) lmax = fmaxf(lmax, __shfl_xor(lmax, m, 64));
  if ((tid & 63) == 0) redk[tid >> 6] = lmax;
  __syncthreads();
  float M = fmaxf(fmaxf(redk[0], redk[1]), fmaxf(redk[2], redk[3]));
  __syncthreads();
  float ssum = 0.f;
  for (int r = 0; r < 4; ++r) ssum += __expf(lg[tid + r*256] - M);
  for (int m = 32; m; m >>= 1) ssum += __shfl_xor(ssum, m, 64);
  if ((tid & 63) == 0) redk[tid >> 6] = ssum;
  __syncthreads();
  float S = redk[0] + redk[1] + redk[2] + redk[3];
  float lse = M + __logf(S);
  for (int r = 0; r < 4; ++r) {
    int cc = tid + r*256;
    out_start[cc] = lg[cc] - lse;
  }
}

// ---------------------------------------------------------------- K2: transition logits GEMM (f32)
__global__ __launch_bounds__(256) void k_gemm_cc(
    const float* __restrict__ A, const float* __restrict__ B, float* __restrict__ Cout)
{
  __shared__ float As[64][69];
  __shared__ float Bs[64][69];
  int tid = threadIdx.x;
  int bi = blockIdx.y, bj = blockIdx.x;
  int sr = tid >> 2, sq = tid & 3;
  int tx = tid & 15, ty = tid >> 4;
  float acc[4][4] = {};
  for (int kb = 0; kb < H_; kb += 64) {
    __syncthreads();
    {
      const float* ar = A + (size_t)(bi*64 + sr)*H_ + kb + sq*16;
      const float* br = B + (size_t)(bj*64 + sr)*H_ + kb + sq*16;
#pragma unroll
      for (int qq = 0; qq < 4; ++qq) {
        float4 av = *(const float4*)(ar + qq*4);
        float4 bv = *(const float4*)(br + qq*4);
        int kk = sq*16 + qq*4;
        As[sr][kk+0]=av.x; As[sr][kk+1]=av.y; As[sr][kk+2]=av.z; As[sr][kk+3]=av.w;
        Bs[sr][kk+0]=bv.x; Bs[sr][kk+1]=bv.y; Bs[sr][kk+2]=bv.z; Bs[sr][kk+3]=bv.w;
      }
    }
    __syncthreads();
#pragma unroll 4
    for (int k = 0; k < 64; ++k) {
      float a0 = As[ty*4+0][k], a1 = As[ty*4+1][k], a2 = As[ty*4+2][k], a3 = As[ty*4+3][k];
      float b0 = Bs[tx*4+0][k], b1 = Bs[tx*4+1][k], b2 = Bs[tx*4+2][k], b3 = Bs[tx*4+3][k];
      acc[0][0]+=a0*b0; acc[0][1]+=a0*b1; acc[0][2]+=a0*b2; acc[0][3]+=a0*b3;
      acc[1][0]+=a1*b0; acc[1][1]+=a1*b1; acc[1][2]+=a1*b2; acc[1][3]+=a1*b3;
      acc[2][0]+=a2*b0; acc[2][1]+=a2*b1; acc[2][2]+=a2*b2; acc[2][3]+=a2*b3;
      acc[3][0]+=a3*b0; acc[3][1]+=a3*b1; acc[3][2]+=a3*b2; acc[3][3]+=a3*b3;
    }
  }
#pragma unroll
  for (int ii = 0; ii < 4; ++ii)
#pragma unroll
    for (int jj = 0; jj < 4; ++jj)
      Cout[(size_t)(bi*64 + ty*4 + ii)*C_ + bj*64 + tx*4 + jj] = acc[ii][jj];
}

// ---------------------------------------------------------------- K3: row softmax in place
__global__ __launch_bounds__(256) void k_softmax_rows(float* __restrict__ P)
{
  __shared__ float redk[4];
  int row = blockIdx.x, tid = threadIdx.x;
  float4* pr = (float4*)(P + (size_t)row*C_);
  float4 v = pr[tid];
  float m = fmaxf(fmaxf(v.x, v.y), fmaxf(v.z, v.w));
  for (int mm = 32; mm; mm >>= 1) m = fmaxf(m, __shfl_xor(m, mm, 64));
  if ((tid & 63) == 0) redk[tid >> 6] = m;
  __syncthreads();
  float M = fmaxf(fmaxf(redk[0], redk[1]), fmaxf(redk[2], redk[3]));
  __syncthreads();
  float4 e;
  e.x = __expf(v.x - M); e.y = __expf(v.y - M); e.z = __expf(v.z - M); e.w = __expf(v.w - M);
  float s = e.x + e.y + e.z + e.w;
  for (int mm = 32; mm; mm >>= 1) s += __shfl_xor(s, mm, 64);
  if ((tid & 63) == 0) redk[tid >> 6] = s;
  __syncthreads();
  float S = redk[0] + redk[1] + redk[2] + redk[3];
  float inv = 1.0f / S;
  e.x *= inv; e.y *= inv; e.z *= inv; e.w *= inv;
  pr[tid] = e;
}

// ---------------------------------------------------------------- K4: terminal MLP
__global__ __launch_bounds__(256) void k_mlp(
    const float* __restrict__ inp, const float* __restrict__ W1, const float* __restrict__ b1,
    const float* __restrict__ W2, const float* __restrict__ b2, float* __restrict__ ft)
{
  __shared__ float xs[4][H_];
  __shared__ float hs[4][H_];
  int tid = threadIdx.x;
  int r0 = blockIdx.x * 4;
  int lr = tid >> 6, lc = (tid & 63) * 4;
  *(float4*)&xs[lr][lc] = *(const float4*)(inp + (size_t)(r0+lr)*H_ + lc);
  __syncthreads();
  for (int L = 0; L < 2; ++L) {
    {
      const float4* wr = (const float4*)(W1 + (size_t)(L*H_ + tid)*H_);
      float bb = b1[L*H_ + tid];
      float a0=bb, a1=bb, a2=bb, a3=bb;
      for (int k = 0; k < H_/4; ++k) {
        float4 w = wr[k];
        a0 += dot4(w, *(const float4*)&xs[0][k*4]);
        a1 += dot4(w, *(const float4*)&xs[1][k*4]);
        a2 += dot4(w, *(const float4*)&xs[2][k*4]);
        a3 += dot4(w, *(const float4*)&xs[3][k*4]);
      }
      hs[0][tid]=fmaxf(a0,0.f); hs[1][tid]=fmaxf(a1,0.f);
      hs[2][tid]=fmaxf(a2,0.f); hs[3][tid]=fmaxf(a3,0.f);
    }
    __syncthreads();
    {
      const float4* wr = (const float4*)(W2 + (size_t)(L*H_ + tid)*H_);
      float bb = b2[L*H_ + tid];
      float a0=bb, a1=bb, a2=bb, a3=bb;
      for (int k = 0; k < H_/4; ++k) {
        float4 w = wr[k];
        a0 += dot4(w, *(const float4*)&hs[0][k*4]);
        a1 += dot4(w, *(const float4*)&hs[1][k*4]);
        a2 += dot4(w, *(const float4*)&hs[2][k*4]);
        a3 += dot4(w, *(const float4*)&hs[3][k*4]);
      }
      xs[0][tid] += fmaxf(a0,0.f); xs[1][tid] += fmaxf(a1,0.f);
      xs[2][tid] += fmaxf(a2,0.f); xs[3][tid] += fmaxf(a3,0.f);
    }
    __syncthreads();
  }
  *(float4*)(ft + (size_t)(r0+lr)*H_ + lc) = *(float4*)&xs[lr][lc];
}

// ---------------------------------------------------------------- K5: emission LSE via MFMA
// logits are tiny (|x| < ~1): no max-subtraction needed, accumulate sum(exp) directly.
#define LSE_VSPLIT 16
#define LSE_VPB    2000
#define LSE_CHUNKS 125

__global__ __launch_bounds__(256) void k_lse_mfma(
    const float* __restrict__ ft, const float* __restrict__ emb, float* __restrict__ part)
{
  int tid = threadIdx.x;
  int lane = tid & 63;
  int w = tid >> 6;
  int q = blockIdx.x;
  int jb = blockIdx.y * 64 + w * 16;
  int r16 = lane & 15, kb = lane >> 4;

  short8 A[8];
  {
    const float* arow = ft + (size_t)(jb + r16) * H_ + kb * 8;
#pragma unroll
    for (int ks = 0; ks < 8; ++ks) {
      float4 a = *(const float4*)(arow + ks * 32);
      float4 b = *(const float4*)(arow + ks * 32 + 4);
      A[ks] = pack8(a, b);
    }
  }
  float s0 = 0.f, s1 = 0.f, s2 = 0.f, s3 = 0.f;
  const float* embq = emb + (size_t)q * LSE_VPB * H_;
#pragma unroll 1
  for (int ch = 0; ch < LSE_CHUNKS; ++ch) {
    const float* brow = embq + (size_t)(ch * 16 + r16) * H_ + kb * 8;
    floatx4 acca = {0,0,0,0}, accb = {0,0,0,0};
#pragma unroll
    for (int ks = 0; ks < 8; ks += 2) {
      float4 x0 = *(const float4*)(brow + ks * 32);
      float4 y0 = *(const float4*)(brow + ks * 32 + 4);
      float4 x1 = *(const float4*)(brow + ks * 32 + 32);
      float4 y1 = *(const float4*)(brow + ks * 32 + 36);
      acca = __builtin_amdgcn_mfma_f32_16x16x32_bf16(A[ks],   pack8(x0, y0), acca, 0, 0, 0);
      accb = __builtin_amdgcn_mfma_f32_16x16x32_bf16(A[ks+1], pack8(x1, y1), accb, 0, 0, 0);
    }
    s0 += __expf(acca[0] + accb[0]);
    s1 += __expf(acca[1] + accb[1]);
    s2 += __expf(acca[2] + accb[2]);
    s3 += __expf(acca[3] + accb[3]);
  }
  // reduce over the 16 cols (lanes differing in bits 0..3)
#pragma unroll
  for (int mm = 1; mm <= 8; mm <<= 1) {
    s0 += __shfl_xor(s0, mm, 64);
    s1 += __shfl_xor(s1, mm, 64);
    s2 += __shfl_xor(s2, mm, 64);
    s3 += __shfl_xor(s3, mm, 64);
  }
  if (r16 == 0) {
    int jrow = jb + kb * 4;
    part[(size_t)(jrow + 0) * LSE_VSPLIT + q] = s0;
    part[(size_t)(jrow + 1) * LSE_VSPLIT + q] = s1;
    part[(size_t)(jrow + 2) * LSE_VSPLIT + q] = s2;
    part[(size_t)(jrow + 3) * LSE_VSPLIT + q] = s3;
  }
}

// ---------------------------------------------------------------- K6: combine LSE partials
__global__ __launch_bounds__(256) void k_lse_reduce(
    const float* __restrict__ part, float* __restrict__ lse_row)
{
  int row = blockIdx.x * 256 + threadIdx.x;
  const float4* p = (const float4*)(part + (size_t)row * LSE_VSPLIT);
  float4 a = p[0], b = p[1], c = p[2], d = p[3];
  float s = a.x+a.y+a.z+a.w + b.x+b.y+b.z+b.w + c.x+c.y+c.z+c.w + d.x+d.y+d.z+d.w;
  lse_row[row] = __logf(s);
}

// ---------------------------------------------------------------- K7: EEXP via MFMA (gathered B)
__global__ __launch_bounds__(256) void k_eexp_mfma(
    const float* __restrict__ ft, const float* __restrict__ emb, const int* __restrict__ text,
    const float* __restrict__ lse_row, float* __restrict__ EEXP)
{
  int tid = threadIdx.x;
  int lane = tid & 63;
  int w = tid >> 6;
  int jb = blockIdx.y * 64 + w * 16;
  int tb = blockIdx.x * 64;
  int r16 = lane & 15, kb = lane >> 4;

  short8 A[8];
  {
    const float* arow = ft + (size_t)(jb + r16) * H_ + kb * 8;
#pragma unroll
    for (int ks = 0; ks < 8; ++ks) {
      float4 a = *(const float4*)(arow + ks * 32);
      float4 b = *(const float4*)(arow + ks * 32 + 4);
      A[ks] = pack8(a, b);
    }
  }
  float4 lsej = *(const float4*)(lse_row + jb + kb * 4);

#pragma unroll 1
  for (int tc = 0; tc < 4; ++tc) {
    int idx = tb + tc * 16 + r16;
    int tok = text[idx];
    const float* brow = emb + (size_t)tok * H_ + kb * 8;
    floatx4 acca = {0,0,0,0}, accb = {0,0,0,0};
#pragma unroll
    for (int ks = 0; ks < 8; ks += 2) {
      float4 x0 = *(const float4*)(brow + ks * 32);
      float4 y0 = *(const float4*)(brow + ks * 32 + 4);
      float4 x1 = *(const float4*)(brow + ks * 32 + 32);
      float4 y1 = *(const float4*)(brow + ks * 32 + 36);
      acca = __builtin_amdgcn_mfma_f32_16x16x32_bf16(A[ks],   pack8(x0, y0), acca, 0, 0, 0);
      accb = __builtin_amdgcn_mfma_f32_16x16x32_bf16(A[ks+1], pack8(x1, y1), accb, 0, 0, 0);
    }
    float4 o;
    o.x = __expf(acca[0] + accb[0] - lsej.x);
    o.y = __expf(acca[1] + accb[1] - lsej.y);
    o.z = __expf(acca[2] + accb[2] - lsej.z);
    o.w = __expf(acca[3] + accb[3] - lsej.w);
    *(float4*)(EEXP + (size_t)idx * C_ + jb + kb * 4) = o;
  }
}

// ---------------------------------------------------------------- K8: persistent scan, wave-autonomous
// 128 WGs = 32 chunks x 4 groups (round-2 proven topology: c=bid>>2, ng=bid&3).
// Each WAVE is an independent consumer: wave w -> seq s=w>>1 (of group pair),
// col-half h=w&1 (16 cols). Wave polls its seq's FULL 1024 alpha words
// (lane l owns block b=l>>1, 16 words via 8 u64 loads; pair-ballot detection),
// OOO-ingests arrived blocks via wave-private LDS bounce -> 1 MFMA each
// (A rows replicated), computes the per-seq global max itself (order-independent
// -> identical across waves), finalizes 16 cols. NO __syncthreads in the loop,
// no cross-wave reduce, waves slip independently.
// LDS: Pl 64KB [col32][k1024] bf16 swz((col&15)<<4); Bl 8KB [wave][block32][64B].
#define SCAN_LDS (65536 + 8192)

__global__ __launch_bounds__(256) void k_scan(
    const float* __restrict__ P, const float* __restrict__ EEXP, const float* __restrict__ startv,
    unsigned* __restrict__ eaG, float* __restrict__ evp)
{
  extern __shared__ char smem[];
  char* Pl = smem;               // 65536 B
  char* Bl = smem + 65536;       // 8192 B

  int tid  = threadIdx.x;
  int bid  = blockIdx.x;
  int c    = bid >> 2;          // chunk 0..31
  int ng   = bid & 3;           // group 0..3
  int n0   = ng * 2;
  int lane = tid & 63;
  int w    = tid >> 6;          // wave 0..3
  int sq   = w >> 1;            // seq-in-pair 0/1
  int h    = w & 1;             // col half 0/1
  int seq  = n0 + sq;

  // ---- t = 0: alpha_0 for own columns (tag 1), before P staging
  if (tid < 64) {
    int s0i = tid >> 5, j = tid & 31;
    int col = c*CW + j;
    float val = __expf(startv[col]) * EEXP[((size_t)(n0+s0i)*T_ + 0)*C_ + col];
    unsigned word = ((unsigned)f2bf(val) << 16) | 1u;
    __hip_atomic_store(&eaG[(size_t)(0*N_ + n0+s0i)*C_ + col], word,
                       __ATOMIC_RELAXED, __HIP_MEMORY_SCOPE_AGENT);
  }

  // ---- stage P slice -> Pl bf16 [col][k], byte = col*2048 + (2k ^ ((col&15)<<4))
  {
    int j4 = (tid & 7) * 4;
    int irow = tid >> 3;
    for (int rep = 0; rep < 32; ++rep) {
      int i = rep*32 + irow;
      float4 v = *(const float4*)(P + (size_t)i*C_ + c*CW + j4);
      int ib = 2*i;
      *(unsigned short*)(Pl + (size_t)(j4+0)*2048 + (ib ^ (((j4+0)&15)<<4))) = f2bf(v.x);
      *(unsigned short*)(Pl + (size_t)(j4+1)*2048 + (ib ^ (((j4+1)&15)<<4))) = f2bf(v.y);
      *(unsigned short*)(Pl + (size_t)(j4+2)*2048 + (ib ^ (((j4+2)&15)<<4))) = f2bf(v.z);
      *(unsigned short*)(Pl + (size_t)(j4+3)*2048 + (ib ^ (((j4+3)&15)<<4))) = f2bf(v.w);
    }
  }
  __syncthreads();

  float ls = 0.f;                          // per-wave logscale for its seq
  const unsigned long long TMASK = 0x0000ffff0000ffffULL;

  // wave-constant addressing
  int myb  = lane >> 1;                    // owned k-block 0..31
  int half = lane & 1;                     // which 16-word half of the block
  int j0   = lane & 15;
  int col  = h*16 + j0;
  const char* bp = Pl + (size_t)col * 2048;
  int jswz = j0 << 4;
  int ks16 = (lane >> 4) * 16;             // A/B k sub-offset in bytes
  char* bw = Bl + w*2048;                  // wave-private bounce [32][64B]
  int fcol = c*CW + h*16 + j0;             // global col (lanes 0-15 finalize)
  unsigned long long* psrc0 =
      (unsigned long long*)(eaG + (size_t)seq*C_) + (size_t)myb*16 + half*8;
  unsigned long long* psrc1 =
      (unsigned long long*)(eaG + (size_t)(N_ + seq)*C_) + (size_t)myb*16 + half*8;

#pragma unroll 1
  for (int t = 1; t < T_; ++t) {
    int pprev = (t-1) & 1, pcur = t & 1;

    float eexp_reg = 0.f;
    if (lane < 16)
      eexp_reg = EEXP[((size_t)seq*T_ + t)*C_ + fcol];

    unsigned long long* src = pprev ? psrc1 : psrc0;
    unsigned long long tpair = (unsigned long long)(unsigned)t
                             | ((unsigned long long)(unsigned)t << 32);

    floatx4 acc = {0,0,0,0};
    float m = 0.f;                         // alpha >= 0
    unsigned long long pend = 0x5555555555555555ULL;   // even-bit per-block mask
    bool mydone = false;
    int guard = 0;

    while (pend) {
      if (!mydone) {
        unsigned long long v[8];
#pragma unroll
        for (int j = 0; j < 8; ++j)
          v[j] = __hip_atomic_load(src + j, __ATOMIC_RELAXED, __HIP_MEMORY_SCOPE_AGENT);
        bool ok = true;
#pragma unroll
        for (int j = 0; j < 8; ++j) ok &= ((v[j] & TMASK) == tpair);
        if (ok) {
          unsigned pk[8];
#pragma unroll
          for (int j = 0; j < 8; ++j) {
            unsigned lo = (unsigned)v[j], hi = (unsigned)(v[j] >> 32);
            m = fmaxf(m, fmaxf(__uint_as_float(lo & 0xffff0000u),
                               __uint_as_float(hi & 0xffff0000u)));
            pk[j] = (lo >> 16) | (hi & 0xffff0000u);
          }
          *(uint4*)(bw + myb*64 + half*32)      = *(const uint4*)&pk[0];
          *(uint4*)(bw + myb*64 + half*32 + 16) = *(const uint4*)&pk[4];
          mydone = true;
        }
      }
      unsigned long long bal = __ballot(mydone);
      unsigned long long rdy = bal & (bal >> 1) & 0x5555555555555555ULL;
      unsigned long long newm = rdy & pend;
      if (newm) {
        asm volatile("s_waitcnt lgkmcnt(0)" ::: "memory");
        __builtin_amdgcn_sched_barrier(0);
#pragma unroll
        for (int b = 0; b < 32; ++b) if ((newm >> (2*b)) & 1) {
          short8 af = *(const short8*)(bw + b*64 + ks16);
          int off = (b*64 + ks16) ^ jswz;
          short8 bf = *(const short8*)(bp + off);
          acc = __builtin_amdgcn_mfma_f32_16x16x32_bf16(af, bf, acc, 0, 0, 0);
        }
        pend &= ~newm;
      } else {
        __builtin_amdgcn_s_sleep(1);
        if (++guard > 1000000) break;
      }
    }

    // ---- wave-wide max over the full alpha row (order-independent, exact)
#pragma unroll
    for (int mm = 1; mm <= 32; mm <<= 1) m = fmaxf(m, __shfl_xor(m, mm, 64));
    ls += __logf(m);

    // ---- finalize: lanes 0-15 hold C row 0 (col = j0) in acc[0]
    if (lane < 16) {
      float val = (acc[0] / m) * eexp_reg;
      unsigned word = ((unsigned)f2bf(val) << 16) | (unsigned)(t+1);
      __hip_atomic_store(&eaG[(size_t)(pcur*N_ + seq)*C_ + fcol], word,
                         __ATOMIC_RELAXED, __HIP_MEMORY_SCOPE_AGENT);
    }
  }

  // ---- tail: chunk-0 WGs, h==0 waves gather alpha_{T-1} for their seq
  if (c == 0 && h == 0) {
    unsigned long long tpair = (unsigned long long)(unsigned)T_
                             | ((unsigned long long)(unsigned)T_ << 32);
    unsigned long long v[8];
    int guard = 0;
    for (;;) {
#pragma unroll
      for (int j = 0; j < 8; ++j)
        v[j] = __hip_atomic_load(psrc1 + j, __ATOMIC_RELAXED, __HIP_MEMORY_SCOPE_AGENT);
      bool ok = true;
#pragma unroll
      for (int j = 0; j < 8; ++j) ok &= ((v[j] & TMASK) == tpair);
      if (__ballot(ok) == ~0ull) break;
      __builtin_amdgcn_s_sleep(1);
      if (++guard > 1000000) break;
    }
    float ssum = 0.f;
#pragma unroll
    for (int j = 0; j < 8; ++j) {
      ssum += __uint_as_float((unsigned)v[j]        & 0xffff0000u);
      ssum += __uint_as_float((unsigned)(v[j] >> 32) & 0xffff0000u);
    }
#pragma unroll
    for (int mm = 1; mm <= 32; mm <<= 1) ssum += __shfl_xor(ssum, mm, 64);
    if (lane == 0) evp[seq] = ls + __logf(ssum);
  }
}

// ---------------------------------------------------------------- K9: final sum
__global__ void k_final(const float* __restrict__ evp, float* __restrict__ out)
{
  if (threadIdx.x == 0) {
    float s = 0.f;
#pragma unroll
    for (int i = 0; i < N_; ++i) s += evp[i];
    out[0] = s;
  }
}

// ----------------------------------------------------------------
extern "C" void kernel_launch(void* const* d_in, const int* in_sizes, int n_in,
                              void* d_out, int out_size, void* d_ws, size_t ws_size,
                              hipStream_t stream)
{
  const int*   text      = (const int*)  d_in[0];
  const float* start_emb = (const float*)d_in[1];
  const float* slw       = (const float*)d_in[2];
  const float* slb       = (const float*)d_in[3];
  const float* sW1       = (const float*)d_in[4];
  const float* sb1       = (const float*)d_in[5];
  const float* sW2       = (const float*)d_in[6];
  const float* sb2       = (const float*)d_in[7];
  const float* state_emb = (const float*)d_in[8];
  const float* nse       = (const float*)d_in[9];
  const float* pre_emb   = (const float*)d_in[10];
  const float* tW1       = (const float*)d_in[11];
  const float* tb1       = (const float*)d_in[12];
  const float* tW2       = (const float*)d_in[13];
  const float* tb2       = (const float*)d_in[14];
  const float* term_emb  = (const float*)d_in[15];

  char* ws = (char*)d_ws;
  float*    w_start = (float*)   (ws + OFF_START);
  float*    w_lse   = (float*)   (ws + OFF_LSE);
  float*    w_evp   = (float*)   (ws + OFF_EVP);
  unsigned* w_ea    = (unsigned*)(ws + OFF_EA);
  float*    w_ft    = (float*)   (ws + OFF_FT);
  float*    w_P     = (float*)   (ws + OFF_P);
  float*    w_part  = (float*)   (ws + OFF_PART);
  float*    w_eexp  = (float*)   (ws + OFF_EEXP);

  (void)hipMemsetAsync(w_ea, 0, 2*N_*C_*sizeof(unsigned), stream);

  k_start<<<1, 256, 0, stream>>>(start_emb, slw, slb, sW1, sb1, sW2, sb2, nse, w_start);
  k_gemm_cc<<<dim3(16,16), 256, 0, stream>>>(state_emb, nse, w_P);
  k_softmax_rows<<<C_, 256, 0, stream>>>(w_P);
  k_mlp<<<C_/4, 256, 0, stream>>>(pre_emb, tW1, tb1, tW2, tb2, w_ft);
  k_lse_mfma<<<dim3(LSE_VSPLIT, 16), 256, 0, stream>>>(w_ft, term_emb, w_part);
  k_lse_reduce<<<4, 256, 0, stream>>>(w_part, w_lse);
  k_eexp_mfma<<<dim3(64, 16), 256, 0, stream>>>(w_ft, term_emb, text, w_lse, w_eexp);

  (void)hipFuncSetAttribute((const void*)k_scan, hipFuncAttributeMaxDynamicSharedMemorySize, SCAN_LDS);
  k_scan<<<128, 256, SCAN_LDS, stream>>>(w_P, w_eexp, w_start, w_ea, w_evp);
  k_final<<<1, 64, 0, stream>>>(w_evp, (float*)d_out);
}

// Round 5
// 1653.679 us; speedup vs baseline: 1.5597x; 1.5597x over previous
//
#include <hip/hip_runtime.h>
#include <stdint.h>
#include <stddef.h>

#define N_ 8
#define T_ 512
#define C_ 1024
#define H_ 256
#define V_ 32000

// workspace byte offsets
#define OFF_START   0u
#define OFF_LSE     4096u
#define OFF_EVP     8192u        // 8 f32 per-seq evidence
#define OFF_FT      81920u       // 1024*256 f32 = 1MB
#define OFF_P       1130496u     // 1024*1024 f32 = 4MB
#define OFF_PART    5324800u     // 1024*16 f32 partials
#define OFF_EEXP    5849088u     // 4096*1024 f32 = 16MB
#define OFF_BUF     22626304u    // 3 bufs x 4 grp x 2 seq x 1024 f32 = 98304 B
#define OFF_FLAGS   22724608u    // 4 grp x 32 u32 = 512 B

typedef __attribute__((ext_vector_type(8))) short short8;
typedef __attribute__((ext_vector_type(4))) float floatx4;

__device__ __forceinline__ float dot4(float4 a, float4 b) {
  return a.x*b.x + a.y*b.y + a.z*b.z + a.w*b.w;
}

__device__ __forceinline__ unsigned short f2bf(float f) {
  unsigned u = __float_as_uint(f);
  unsigned r = u + 0x7fffu + ((u >> 16) & 1u);   // round-to-nearest-even
  return (unsigned short)(r >> 16);
}

__device__ __forceinline__ unsigned pk_bf2(float x, float y) {
  return ((unsigned)f2bf(y) << 16) | (unsigned)f2bf(x);
}

__device__ __forceinline__ short8 pack8(float4 a, float4 b) {
  union { short8 s; unsigned u[4]; } r;
  r.u[0] = pk_bf2(a.x, a.y);
  r.u[1] = pk_bf2(a.z, a.w);
  r.u[2] = pk_bf2(b.x, b.y);
  r.u[3] = pk_bf2(b.z, b.w);
  return r.s;
}

// ---------------------------------------------------------------- K1: start distribution
__global__ __launch_bounds__(256) void k_start(
    const float* __restrict__ se, const float* __restrict__ lw, const float* __restrict__ lb,
    const float* __restrict__ W1, const float* __restrict__ b1,
    const float* __restrict__ W2, const float* __restrict__ b2,
    const float* __restrict__ nse, float* __restrict__ out_start)
{
  __shared__ float xs[H_], fx[H_], h1[H_];
  __shared__ float lg[C_];
  __shared__ float redk[4];
  int tid = threadIdx.x;
  xs[tid] = se[tid];
  __syncthreads();
  {
    float acc = lb[tid];
    const float4* wr = (const float4*)(lw + (size_t)tid*H_);
    for (int k = 0; k < H_/4; ++k) acc += dot4(wr[k], *(const float4*)&xs[k*4]);
    fx[tid] = acc;
  }
  __syncthreads();
  for (int L = 0; L < 2; ++L) {
    {
      float acc = b1[L*H_ + tid];
      const float4* wr = (const float4*)(W1 + (size_t)(L*H_ + tid)*H_);
      for (int k = 0; k < H_/4; ++k) acc += dot4(wr[k], *(const float4*)&fx[k*4]);
      h1[tid] = fmaxf(acc, 0.f);
    }
    __syncthreads();
    {
      float acc = b2[L*H_ + tid];
      const float4* wr = (const float4*)(W2 + (size_t)(L*H_ + tid)*H_);
      for (int k = 0; k < H_/4; ++k) acc += dot4(wr[k], *(const float4*)&h1[k*4]);
      fx[tid] += fmaxf(acc, 0.f);
    }
    __syncthreads();
  }
  float lmax = -1e30f;
  for (int r = 0; r < 4; ++r) {
    int cc = tid + r*256;
    float acc = 0.f;
    const float4* er = (const float4*)(nse + (size_t)cc*H_);
    for (int k = 0; k < H_/4; ++k) acc += dot4(er[k], *(const float4*)&fx[k*4]);
    lg[cc] = acc;
    lmax = fmaxf(lmax, acc);
  }
  for (int m = 32; m; m >>= 1) lmax = fmaxf(lmax, __shfl_xor(lmax, m, 64));
  if ((tid & 63) == 0) redk[tid >> 6] = lmax;
  __syncthreads();
  float M = fmaxf(fmaxf(redk[0], redk[1]), fmaxf(redk[2], redk[3]));
  __syncthreads();
  float ssum = 0.f;
  for (int r = 0; r < 4; ++r) ssum += __expf(lg[tid + r*256] - M);
  for (int m = 32; m; m >>= 1) ssum += __shfl_xor(ssum, m, 64);
  if ((tid & 63) == 0) redk[tid >> 6] = ssum;
  __syncthreads();
  float S = redk[0] + redk[1] + redk[2] + redk[3];
  float lse = M + __logf(S);
  for (int r = 0; r < 4; ++r) {
    int cc = tid + r*256;
    out_start[cc] = lg[cc] - lse;
  }
}

// ---------------------------------------------------------------- K2: transition logits GEMM (f32)
__global__ __launch_bounds__(256) void k_gemm_cc(
    const float* __restrict__ A, const float* __restrict__ B, float* __restrict__ Cout)
{
  __shared__ float As[64][69];
  __shared__ float Bs[64][69];
  int tid = threadIdx.x;
  int bi = blockIdx.y, bj = blockIdx.x;
  int sr = tid >> 2, sq = tid & 3;
  int tx = tid & 15, ty = tid >> 4;
  float acc[4][4] = {};
  for (int kb = 0; kb < H_; kb += 64) {
    __syncthreads();
    {
      const float* ar = A + (size_t)(bi*64 + sr)*H_ + kb + sq*16;
      const float* br = B + (size_t)(bj*64 + sr)*H_ + kb + sq*16;
#pragma unroll
      for (int qq = 0; qq < 4; ++qq) {
        float4 av = *(const float4*)(ar + qq*4);
        float4 bv = *(const float4*)(br + qq*4);
        int kk = sq*16 + qq*4;
        As[sr][kk+0]=av.x; As[sr][kk+1]=av.y; As[sr][kk+2]=av.z; As[sr][kk+3]=av.w;
        Bs[sr][kk+0]=bv.x; Bs[sr][kk+1]=bv.y; Bs[sr][kk+2]=bv.z; Bs[sr][kk+3]=bv.w;
      }
    }
    __syncthreads();
#pragma unroll 4
    for (int k = 0; k < 64; ++k) {
      float a0 = As[ty*4+0][k], a1 = As[ty*4+1][k], a2 = As[ty*4+2][k], a3 = As[ty*4+3][k];
      float b0 = Bs[tx*4+0][k], b1 = Bs[tx*4+1][k], b2 = Bs[tx*4+2][k], b3 = Bs[tx*4+3][k];
      acc[0][0]+=a0*b0; acc[0][1]+=a0*b1; acc[0][2]+=a0*b2; acc[0][3]+=a0*b3;
      acc[1][0]+=a1*b0; acc[1][1]+=a1*b1; acc[1][2]+=a1*b2; acc[1][3]+=a1*b3;
      acc[2][0]+=a2*b0; acc[2][1]+=a2*b1; acc[2][2]+=a2*b2; acc[2][3]+=a2*b3;
      acc[3][0]+=a3*b0; acc[3][1]+=a3*b1; acc[3][2]+=a3*b2; acc[3][3]+=a3*b3;
    }
  }
#pragma unroll
  for (int ii = 0; ii < 4; ++ii)
#pragma unroll
    for (int jj = 0; jj < 4; ++jj)
      Cout[(size_t)(bi*64 + ty*4 + ii)*C_ + bj*64 + tx*4 + jj] = acc[ii][jj];
}

// ---------------------------------------------------------------- K3: row softmax in place
__global__ __launch_bounds__(256) void k_softmax_rows(float* __restrict__ P)
{
  __shared__ float redk[4];
  int row = blockIdx.x, tid = threadIdx.x;
  float4* pr = (float4*)(P + (size_t)row*C_);
  float4 v = pr[tid];
  float m = fmaxf(fmaxf(v.x, v.y), fmaxf(v.z, v.w));
  for (int mm = 32; mm; mm >>= 1) m = fmaxf(m, __shfl_xor(m, mm, 64));
  if ((tid & 63) == 0) redk[tid >> 6] = m;
  __syncthreads();
  float M = fmaxf(fmaxf(redk[0], redk[1]), fmaxf(redk[2], redk[3]));
  __syncthreads();
  float4 e;
  e.x = __expf(v.x - M); e.y = __expf(v.y - M); e.z = __expf(v.z - M); e.w = __expf(v.w - M);
  float s = e.x + e.y + e.z + e.w;
  for (int mm = 32; mm; mm >>= 1) s += __shfl_xor(s, mm, 64);
  if ((tid & 63) == 0) redk[tid >> 6] = s;
  __syncthreads();
  float S = redk[0] + redk[1] + redk[2] + redk[3];
  float inv = 1.0f / S;
  e.x *= inv; e.y *= inv; e.z *= inv; e.w *= inv;
  pr[tid] = e;
}

// ---------------------------------------------------------------- K4: terminal MLP
__global__ __launch_bounds__(256) void k_mlp(
    const float* __restrict__ inp, const float* __restrict__ W1, const float* __restrict__ b1,
    const float* __restrict__ W2, const float* __restrict__ b2, float* __restrict__ ft)
{
  __shared__ float xs[4][H_];
  __shared__ float hs[4][H_];
  int tid = threadIdx.x;
  int r0 = blockIdx.x * 4;
  int lr = tid >> 6, lc = (tid & 63) * 4;
  *(float4*)&xs[lr][lc] = *(const float4*)(inp + (size_t)(r0+lr)*H_ + lc);
  __syncthreads();
  for (int L = 0; L < 2; ++L) {
    {
      const float4* wr = (const float4*)(W1 + (size_t)(L*H_ + tid)*H_);
      float bb = b1[L*H_ + tid];
      float a0=bb, a1=bb, a2=bb, a3=bb;
      for (int k = 0; k < H_/4; ++k) {
        float4 w = wr[k];
        a0 += dot4(w, *(const float4*)&xs[0][k*4]);
        a1 += dot4(w, *(const float4*)&xs[1][k*4]);
        a2 += dot4(w, *(const float4*)&xs[2][k*4]);
        a3 += dot4(w, *(const float4*)&xs[3][k*4]);
      }
      hs[0][tid]=fmaxf(a0,0.f); hs[1][tid]=fmaxf(a1,0.f);
      hs[2][tid]=fmaxf(a2,0.f); hs[3][tid]=fmaxf(a3,0.f);
    }
    __syncthreads();
    {
      const float4* wr = (const float4*)(W2 + (size_t)(L*H_ + tid)*H_);
      float bb = b2[L*H_ + tid];
      float a0=bb, a1=bb, a2=bb, a3=bb;
      for (int k = 0; k < H_/4; ++k) {
        float4 w = wr[k];
        a0 += dot4(w, *(const float4*)&hs[0][k*4]);
        a1 += dot4(w, *(const float4*)&hs[1][k*4]);
        a2 += dot4(w, *(const float4*)&hs[2][k*4]);
        a3 += dot4(w, *(const float4*)&hs[3][k*4]);
      }
      xs[0][tid] += fmaxf(a0,0.f); xs[1][tid] += fmaxf(a1,0.f);
      xs[2][tid] += fmaxf(a2,0.f); xs[3][tid] += fmaxf(a3,0.f);
    }
    __syncthreads();
  }
  *(float4*)(ft + (size_t)(r0+lr)*H_ + lc) = *(float4*)&xs[lr][lc];
}

// ---------------------------------------------------------------- K5: emission LSE via MFMA
#define LSE_VSPLIT 16
#define LSE_VPB    2000
#define LSE_CHUNKS 125

__global__ __launch_bounds__(256) void k_lse_mfma(
    const float* __restrict__ ft, const float* __restrict__ emb, float* __restrict__ part)
{
  int tid = threadIdx.x;
  int lane = tid & 63;
  int w = tid >> 6;
  int q = blockIdx.x;
  int jb = blockIdx.y * 64 + w * 16;
  int r16 = lane & 15, kb = lane >> 4;

  short8 A[8];
  {
    const float* arow = ft + (size_t)(jb + r16) * H_ + kb * 8;
#pragma unroll
    for (int ks = 0; ks < 8; ++ks) {
      float4 a = *(const float4*)(arow + ks * 32);
      float4 b = *(const float4*)(arow + ks * 32 + 4);
      A[ks] = pack8(a, b);
    }
  }
  float s0 = 0.f, s1 = 0.f, s2 = 0.f, s3 = 0.f;
  const float* embq = emb + (size_t)q * LSE_VPB * H_;
#pragma unroll 1
  for (int ch = 0; ch < LSE_CHUNKS; ++ch) {
    const float* brow = embq + (size_t)(ch * 16 + r16) * H_ + kb * 8;
    floatx4 acca = {0,0,0,0}, accb = {0,0,0,0};
#pragma unroll
    for (int ks = 0; ks < 8; ks += 2) {
      float4 x0 = *(const float4*)(brow + ks * 32);
      float4 y0 = *(const float4*)(brow + ks * 32 + 4);
      float4 x1 = *(const float4*)(brow + ks * 32 + 32);
      float4 y1 = *(const float4*)(brow + ks * 32 + 36);
      acca = __builtin_amdgcn_mfma_f32_16x16x32_bf16(A[ks],   pack8(x0, y0), acca, 0, 0, 0);
      accb = __builtin_amdgcn_mfma_f32_16x16x32_bf16(A[ks+1], pack8(x1, y1), accb, 0, 0, 0);
    }
    s0 += __expf(acca[0] + accb[0]);
    s1 += __expf(acca[1] + accb[1]);
    s2 += __expf(acca[2] + accb[2]);
    s3 += __expf(acca[3] + accb[3]);
  }
#pragma unroll
  for (int mm = 1; mm <= 8; mm <<= 1) {
    s0 += __shfl_xor(s0, mm, 64);
    s1 += __shfl_xor(s1, mm, 64);
    s2 += __shfl_xor(s2, mm, 64);
    s3 += __shfl_xor(s3, mm, 64);
  }
  if (r16 == 0) {
    int jrow = jb + kb * 4;
    part[(size_t)(jrow + 0) * LSE_VSPLIT + q] = s0;
    part[(size_t)(jrow + 1) * LSE_VSPLIT + q] = s1;
    part[(size_t)(jrow + 2) * LSE_VSPLIT + q] = s2;
    part[(size_t)(jrow + 3) * LSE_VSPLIT + q] = s3;
  }
}

// ---------------------------------------------------------------- K6: combine LSE partials
__global__ __launch_bounds__(256) void k_lse_reduce(
    const float* __restrict__ part, float* __restrict__ lse_row)
{
  int row = blockIdx.x * 256 + threadIdx.x;
  const float4* p = (const float4*)(part + (size_t)row * LSE_VSPLIT);
  float4 a = p[0], b = p[1], c = p[2], d = p[3];
  float s = a.x+a.y+a.z+a.w + b.x+b.y+b.z+b.w + c.x+c.y+c.z+c.w + d.x+d.y+d.z+d.w;
  lse_row[row] = __logf(s);
}

// ---------------------------------------------------------------- K7: EEXP via MFMA (gathered B)
__global__ __launch_bounds__(256) void k_eexp_mfma(
    const float* __restrict__ ft, const float* __restrict__ emb, const int* __restrict__ text,
    const float* __restrict__ lse_row, float* __restrict__ EEXP)
{
  int tid = threadIdx.x;
  int lane = tid & 63;
  int w = tid >> 6;
  int jb = blockIdx.y * 64 + w * 16;
  int tb = blockIdx.x * 64;
  int r16 = lane & 15, kb = lane >> 4;

  short8 A[8];
  {
    const float* arow = ft + (size_t)(jb + r16) * H_ + kb * 8;
#pragma unroll
    for (int ks = 0; ks < 8; ++ks) {
      float4 a = *(const float4*)(arow + ks * 32);
      float4 b = *(const float4*)(arow + ks * 32 + 4);
      A[ks] = pack8(a, b);
    }
  }
  float4 lsej = *(const float4*)(lse_row + jb + kb * 4);

#pragma unroll 1
  for (int tc = 0; tc < 4; ++tc) {
    int idx = tb + tc * 16 + r16;
    int tok = text[idx];
    const float* brow = emb + (size_t)tok * H_ + kb * 8;
    floatx4 acca = {0,0,0,0}, accb = {0,0,0,0};
#pragma unroll
    for (int ks = 0; ks < 8; ks += 2) {
      float4 x0 = *(const float4*)(brow + ks * 32);
      float4 y0 = *(const float4*)(brow + ks * 32 + 4);
      float4 x1 = *(const float4*)(brow + ks * 32 + 32);
      float4 y1 = *(const float4*)(brow + ks * 32 + 36);
      acca = __builtin_amdgcn_mfma_f32_16x16x32_bf16(A[ks],   pack8(x0, y0), acca, 0, 0, 0);
      accb = __builtin_amdgcn_mfma_f32_16x16x32_bf16(A[ks+1], pack8(x1, y1), accb, 0, 0, 0);
    }
    float4 o;
    o.x = __expf(acca[0] + accb[0] - lsej.x);
    o.y = __expf(acca[1] + accb[1] - lsej.y);
    o.z = __expf(acca[2] + accb[2] - lsej.z);
    o.w = __expf(acca[3] + accb[3] - lsej.w);
    *(float4*)(EEXP + (size_t)idx * C_ + jb + kb * 4) = o;
  }
}

// ---------------------------------------------------------------- K8: persistent scan, DOUBLE-STEP rounds
// 128 WGs = 32 chunks x 4 groups (c = bid>>2, ng = bid&3). Round r handles
// t = 2r+1 (u, chunk-local via P column-slice) and t = 2r+2 (v, full-width
// partial via P row-slice, scatter-reduced with global_atomic_add_f32).
// Detection: 32 flag words per group (tag = r+1, release-ordered by the
// __syncthreads vmcnt-drain before the store). Consumers read the f32 sum
// buffer, apply e_{2r}, max-normalize (identical in all WGs), bf16-pack.
// Buffers rotate mod 3; each WG resets its 64-word slice of buf[(r+1)%3]
// (safe: that buffer's last readers finished round r-1, certified by flags==r).
// Round 0: alpha_0 built locally, no comm. Round 255: single step (u added).
// LDS: Pl 64KB P-cols [col32][k1024] swz; Pr 64KB P-rows [jt][j16][m32];
//      Al 4KB alpha bf16 [blk32][seq2][kk32] swz; red 1KB; Ub 128B; redm 16B.
#define SCAN_LDS 136352

__global__ __launch_bounds__(256) void k_scan(
    const float* __restrict__ P, const float* __restrict__ EEXP, const float* __restrict__ startv,
    float* __restrict__ bufG, unsigned* __restrict__ flagsG, float* __restrict__ evp)
{
  extern __shared__ char smem[];
  char*  Pl   = smem;                         // 65536
  char*  Pr   = smem + 65536;                 // 65536
  char*  Al   = smem + 131072;                // 4096
  float* red  = (float*)(smem + 135168);      // 1024
  char*  Ub   = smem + 136192;                // 128
  float* redm = (float*)(smem + 136320);      // 16

  int tid  = threadIdx.x;
  int bid  = blockIdx.x;
  int c    = bid >> 2;          // chunk 0..31
  int ng   = bid & 3;           // group 0..3
  int n0   = ng * 2;
  int lane = tid & 63;
  int w    = tid >> 6;          // wave 0..3 = K quarter
  int s    = tid >> 7;          // consumer seq 0/1
  int k0   = (tid & 127) * 8;   // consumer k base
  int r16  = lane & 15, kb = lane >> 4;
  int j0   = r16;
  int jswz = j0 << 4;

  unsigned* myflags = flagsG + ng*32;
  float* bufq[3];
  bufq[0] = bufG + (size_t)(0*4 + ng)*2048;
  bufq[1] = bufG + (size_t)(1*4 + ng)*2048;
  bufq[2] = bufG + (size_t)(2*4 + ng)*2048;

  // ---- stage Pl: P columns c*32..+31, bf16 [col][k], byte = col*2048 + (2k ^ ((col&15)<<4))
  {
    int j4 = (tid & 7) * 4;
    int irow = tid >> 3;
    for (int rep = 0; rep < 32; ++rep) {
      int i = rep*32 + irow;
      float4 v = *(const float4*)(P + (size_t)i*C_ + c*32 + j4);
      int ib = 2*i;
      *(unsigned short*)(Pl + (size_t)(j4+0)*2048 + (ib ^ (((j4+0)&15)<<4))) = f2bf(v.x);
      *(unsigned short*)(Pl + (size_t)(j4+1)*2048 + (ib ^ (((j4+1)&15)<<4))) = f2bf(v.y);
      *(unsigned short*)(Pl + (size_t)(j4+2)*2048 + (ib ^ (((j4+2)&15)<<4))) = f2bf(v.z);
      *(unsigned short*)(Pl + (size_t)(j4+3)*2048 + (ib ^ (((j4+3)&15)<<4))) = f2bf(v.w);
    }
  }
  // ---- stage Pr: P rows c*32..+31, bf16 [j>>4][j&15][m], byte = (j>>4)*1024 + (j&15)*64 + m*2
  {
    int jb4 = (tid & 255) * 4;
    for (int m = 0; m < 32; ++m) {
      float4 v = *(const float4*)(P + (size_t)(c*32 + m)*C_ + jb4);
#pragma unroll
      for (int dj = 0; dj < 4; ++dj) {
        int j = jb4 + dj;
        float vv = (dj==0)?v.x:(dj==1)?v.y:(dj==2)?v.z:v.w;
        *(unsigned short*)(Pr + (size_t)(j>>4)*1024 + (j&15)*64 + m*2) = f2bf(vv);
      }
    }
  }

  float ls = 0.f;   // per-thread logscale for its seq (s)

#pragma unroll 1
  for (int r = 0; r < 256; ++r) {
    // producer-side eexp prefetch (t = 2r+1), tid<64 finalize slots
    float ue = 0.f;
    if (tid < 64) {
      int ss = tid >> 5, col = tid & 31;
      ue = EEXP[((size_t)(n0+ss)*T_ + (2*r+1))*C_ + c*32 + col];
    }

    float av[8];
    if (r == 0) {
#pragma unroll
      for (int j = 0; j < 8; ++j)
        av[j] = __expf(startv[k0+j]) * EEXP[((size_t)(n0+s)*T_ + 0)*C_ + k0+j];
    } else {
      // ---- poll flags == r
      int guard = 0;
      for (;;) {
        unsigned f = (lane < 32)
          ? __hip_atomic_load(myflags + lane, __ATOMIC_RELAXED, __HIP_MEMORY_SCOPE_AGENT)
          : (unsigned)r;
        if (__ballot(f == (unsigned)r) == ~0ull) break;
        __builtin_amdgcn_s_sleep(1);
        if (++guard > 2000000) break;
      }
      // ---- read sums (alpha_{2r} pre-e), apply e_{2r}
      float* srcb = bufq[(r-1)%3] + s*1024 + k0;
      float sv[8];
#pragma unroll
      for (int j = 0; j < 8; ++j)
        sv[j] = __hip_atomic_load(srcb + j, __ATOMIC_RELAXED, __HIP_MEMORY_SCOPE_AGENT);
      float4 e0 = *(const float4*)(EEXP + ((size_t)(n0+s)*T_ + 2*r)*C_ + k0);
      float4 e1 = *(const float4*)(EEXP + ((size_t)(n0+s)*T_ + 2*r)*C_ + k0 + 4);
      av[0]=sv[0]*e0.x; av[1]=sv[1]*e0.y; av[2]=sv[2]*e0.z; av[3]=sv[3]*e0.w;
      av[4]=sv[4]*e1.x; av[5]=sv[5]*e1.y; av[6]=sv[6]*e1.z; av[7]=sv[7]*e1.w;
      // ---- reset this WG's slice of buf[(r+1)%3] (safe per flags==r)
      if (tid < 64) {
        int ss = tid >> 5, col = tid & 31;
        __hip_atomic_store(bufq[(r+1)%3] + ss*1024 + c*32 + col, 0.0f,
                           __ATOMIC_RELAXED, __HIP_MEMORY_SCOPE_AGENT);
      }
    }

    // ---- per-seq max (waves 0,1 = seq0; 2,3 = seq1)
    float m = fmaxf(fmaxf(fmaxf(av[0],av[1]),fmaxf(av[2],av[3])),
                    fmaxf(fmaxf(av[4],av[5]),fmaxf(av[6],av[7])));
#pragma unroll
    for (int mm = 1; mm <= 32; mm <<= 1) m = fmaxf(m, __shfl_xor(m, mm, 64));
    if (lane == 0) redm[w] = m;
    __syncthreads();                                        // B1
    float M = fmaxf(redm[s*2], redm[s*2+1]);
    ls += __logf(M);
    float rinv = 1.0f / M;
    // ---- pack normalized alpha to Al: blk*128 + s*64 + ((kk*2) ^ ((blk&3)<<4))
    {
      unsigned pk[4];
      pk[0] = pk_bf2(av[0]*rinv, av[1]*rinv);
      pk[1] = pk_bf2(av[2]*rinv, av[3]*rinv);
      pk[2] = pk_bf2(av[4]*rinv, av[5]*rinv);
      pk[3] = pk_bf2(av[6]*rinv, av[7]*rinv);
      int blk = k0 >> 5;
      *(uint4*)(Al + blk*128 + s*64 + (((k0&31)*2) ^ ((blk&3)<<4))) = *(const uint4*)pk;
    }
    __syncthreads();                                        // B2

    // ---- u-matvec: wave w = K quarter, 2 col-tiles
    floatx4 acc0 = {0,0,0,0}, acc1 = {0,0,0,0};
#pragma unroll
    for (int b = 0; b < 8; ++b) {
      int blk = w*8 + b;
      short8 af = *(const short8*)(Al + blk*128 + (r16&1)*64 + ((kb*16) ^ ((blk&3)<<4)));
      int kby = 2*(blk*32 + kb*8);
      short8 f0 = *(const short8*)(Pl + (size_t)j0*2048 + (kby ^ jswz));
      short8 f1 = *(const short8*)(Pl + (size_t)(16+j0)*2048 + (kby ^ jswz));
      acc0 = __builtin_amdgcn_mfma_f32_16x16x32_bf16(af, f0, acc0, 0, 0, 0);
      acc1 = __builtin_amdgcn_mfma_f32_16x16x32_bf16(af, f1, acc1, 0, 0, 0);
    }
    if (lane < 16) {
      red[((w*2+0)*2+0)*16 + j0] = acc0[0];
      red[((w*2+0)*2+1)*16 + j0] = acc0[1];
      red[((w*2+1)*2+0)*16 + j0] = acc1[0];
      red[((w*2+1)*2+1)*16 + j0] = acc1[1];
    }
    __syncthreads();                                        // B3

    if (r == 255) {
      // ---- final single step: add u (with e_511) directly into buf[255%3]
      if (tid < 64) {
        int ss = tid >> 5, col = tid & 31;
        int tl = col >> 4, c16 = col & 15;
        float usum = red[((0*2+tl)*2+ss)*16 + c16] + red[((1*2+tl)*2+ss)*16 + c16]
                   + red[((2*2+tl)*2+ss)*16 + c16] + red[((3*2+tl)*2+ss)*16 + c16];
        (void)__hip_atomic_fetch_add(bufq[255%3] + ss*1024 + c*32 + col, usum * ue,
                                     __ATOMIC_RELAXED, __HIP_MEMORY_SCOPE_AGENT);
      }
      __syncthreads();                                      // drains adds
      if (tid == 0)
        __hip_atomic_store(myflags + c, 256u, __ATOMIC_RELAXED, __HIP_MEMORY_SCOPE_AGENT);
    } else {
      // ---- finalize u, apply e_{2r+1}, pack bf16 to Ub
      if (tid < 64) {
        int ss = tid >> 5, col = tid & 31;
        int tl = col >> 4, c16 = col & 15;
        float usum = red[((0*2+tl)*2+ss)*16 + c16] + red[((1*2+tl)*2+ss)*16 + c16]
                   + red[((2*2+tl)*2+ss)*16 + c16] + red[((3*2+tl)*2+ss)*16 + c16];
        *(unsigned short*)(Ub + ss*64 + col*2) = f2bf(usum * ue);
      }
      __syncthreads();                                      // B4
      // ---- v-matvec: 16 j-tiles per wave, scatter-reduce via atomic f32 add
      short8 au = *(const short8*)(Ub + (r16&1)*64 + kb*16);
      float* bufp = bufq[r%3];
#pragma unroll 4
      for (int i = 0; i < 16; ++i) {
        int jt = w*16 + i;
        short8 bf = *(const short8*)(Pr + (size_t)jt*1024 + j0*64 + kb*16);
        floatx4 a = {0,0,0,0};
        a = __builtin_amdgcn_mfma_f32_16x16x32_bf16(au, bf, a, 0, 0, 0);
        if (lane < 16) {
          (void)__hip_atomic_fetch_add(bufp + 0*1024 + jt*16 + j0, a[0],
                                       __ATOMIC_RELAXED, __HIP_MEMORY_SCOPE_AGENT);
          (void)__hip_atomic_fetch_add(bufp + 1*1024 + jt*16 + j0, a[1],
                                       __ATOMIC_RELAXED, __HIP_MEMORY_SCOPE_AGENT);
        }
      }
      __syncthreads();                                      // B5: drains all waves' adds
      if (tid == 0)
        __hip_atomic_store(myflags + c, (unsigned)(r+1), __ATOMIC_RELAXED, __HIP_MEMORY_SCOPE_AGENT);
    }
  }

  // ---- tail: chunk-0 WG of each group gathers alpha_511, per-seq logsumexp
  if (c == 0) {
    int guard = 0;
    for (;;) {
      unsigned f = (lane < 32)
        ? __hip_atomic_load(myflags + lane, __ATOMIC_RELAXED, __HIP_MEMORY_SCOPE_AGENT)
        : 256u;
      if (__ballot(f == 256u) == ~0ull) break;
      __builtin_amdgcn_s_sleep(1);
      if (++guard > 2000000) break;
    }
    float* srcb = bufq[255%3] + s*1024 + k0;
    float ssum = 0.f;
#pragma unroll
    for (int j = 0; j < 8; ++j)
      ssum += __hip_atomic_load(srcb + j, __ATOMIC_RELAXED, __HIP_MEMORY_SCOPE_AGENT);
#pragma unroll
    for (int mm = 1; mm <= 32; mm <<= 1) ssum += __shfl_xor(ssum, mm, 64);
    if (lane == 0) redm[w] = ssum;
    __syncthreads();
    if (tid == 0)   evp[n0]     = ls + __logf(redm[0] + redm[1]);
    if (tid == 128) evp[n0 + 1] = ls + __logf(redm[2] + redm[3]);
  }
}

// ---------------------------------------------------------------- K9: final sum
__global__ void k_final(const float* __restrict__ evp, float* __restrict__ out)
{
  if (threadIdx.x == 0) {
    float s = 0.f;
#pragma unroll
    for (int i = 0; i < N_; ++i) s += evp[i];
    out[0] = s;
  }
}

// ----------------------------------------------------------------
extern "C" void kernel_launch(void* const* d_in, const int* in_sizes, int n_in,
                              void* d_out, int out_size, void* d_ws, size_t ws_size,
                              hipStream_t stream)
{
  const int*   text      = (const int*)  d_in[0];
  const float* start_emb = (const float*)d_in[1];
  const float* slw       = (const float*)d_in[2];
  const float* slb       = (const float*)d_in[3];
  const float* sW1       = (const float*)d_in[4];
  const float* sb1       = (const float*)d_in[5];
  const float* sW2       = (const float*)d_in[6];
  const float* sb2       = (const float*)d_in[7];
  const float* state_emb = (const float*)d_in[8];
  const float* nse       = (const float*)d_in[9];
  const float* pre_emb   = (const float*)d_in[10];
  const float* tW1       = (const float*)d_in[11];
  const float* tb1       = (const float*)d_in[12];
  const float* tW2       = (const float*)d_in[13];
  const float* tb2       = (const float*)d_in[14];
  const float* term_emb  = (const float*)d_in[15];

  char* ws = (char*)d_ws;
  float*    w_start = (float*)   (ws + OFF_START);
  float*    w_lse   = (float*)   (ws + OFF_LSE);
  float*    w_evp   = (float*)   (ws + OFF_EVP);
  float*    w_ft    = (float*)   (ws + OFF_FT);
  float*    w_P     = (float*)   (ws + OFF_P);
  float*    w_part  = (float*)   (ws + OFF_PART);
  float*    w_eexp  = (float*)   (ws + OFF_EEXP);
  float*    w_buf   = (float*)   (ws + OFF_BUF);
  unsigned* w_flags = (unsigned*)(ws + OFF_FLAGS);

  // zero sum buffers + flags (regions untouched by other kernels)
  (void)hipMemsetAsync(ws + OFF_BUF, 0, 98304 + 512, stream);

  k_start<<<1, 256, 0, stream>>>(start_emb, slw, slb, sW1, sb1, sW2, sb2, nse, w_start);
  k_gemm_cc<<<dim3(16,16), 256, 0, stream>>>(state_emb, nse, w_P);
  k_softmax_rows<<<C_, 256, 0, stream>>>(w_P);
  k_mlp<<<C_/4, 256, 0, stream>>>(pre_emb, tW1, tb1, tW2, tb2, w_ft);
  k_lse_mfma<<<dim3(LSE_VSPLIT, 16), 256, 0, stream>>>(w_ft, term_emb, w_part);
  k_lse_reduce<<<4, 256, 0, stream>>>(w_part, w_lse);
  k_eexp_mfma<<<dim3(64, 16), 256, 0, stream>>>(w_ft, term_emb, text, w_lse, w_eexp);

  (void)hipFuncSetAttribute((const void*)k_scan, hipFuncAttributeMaxDynamicSharedMemorySize, SCAN_LDS);
  k_scan<<<128, 256, SCAN_LDS, stream>>>(w_P, w_eexp, w_start, w_buf, w_flags, w_evp);
  k_final<<<1, 64, 0, stream>>>(w_evp, (float*)d_out);
}

// Round 6
// 1607.757 us; speedup vs baseline: 1.6042x; 1.0286x over previous
//
#include <hip/hip_runtime.h>
#include <stdint.h>
#include <stddef.h>

#define N_ 8
#define T_ 512
#define C_ 1024
#define H_ 256
#define V_ 32000

// workspace byte offsets
#define OFF_START   0u
#define OFF_LSE     4096u
#define OFF_EVP     8192u        // 8 f32 per-seq evidence
#define OFF_FT      81920u       // 1024*256 f32 = 1MB
#define OFF_P       1130496u     // 1024*1024 f32 = 4MB
#define OFF_PART    5324800u     // 1024*16 f32 partials
#define OFF_EEXP    5849088u     // 4096*1024 f32 = 16MB
#define OFF_BUF     22626304u    // 3 bufs x 4 grp x 2 seq x 1024 f32 = 98304 B
#define OFF_CNT     22724608u    // 4 grp x 16 u32 (padded) = 256 B
#define OFF_PT      22725120u    // P^T bf16 [j][m] = 2MB

typedef __attribute__((ext_vector_type(8))) short short8;
typedef __attribute__((ext_vector_type(4))) float floatx4;

__device__ __forceinline__ float dot4(float4 a, float4 b) {
  return a.x*b.x + a.y*b.y + a.z*b.z + a.w*b.w;
}

__device__ __forceinline__ unsigned short f2bf(float f) {
  unsigned u = __float_as_uint(f);
  unsigned r = u + 0x7fffu + ((u >> 16) & 1u);   // round-to-nearest-even
  return (unsigned short)(r >> 16);
}

__device__ __forceinline__ unsigned pk_bf2(float x, float y) {
  return ((unsigned)f2bf(y) << 16) | (unsigned)f2bf(x);
}

__device__ __forceinline__ short8 pack8(float4 a, float4 b) {
  union { short8 s; unsigned u[4]; } r;
  r.u[0] = pk_bf2(a.x, a.y);
  r.u[1] = pk_bf2(a.z, a.w);
  r.u[2] = pk_bf2(b.x, b.y);
  r.u[3] = pk_bf2(b.z, b.w);
  return r.s;
}

// ---------------------------------------------------------------- K1: start distribution
__global__ __launch_bounds__(256) void k_start(
    const float* __restrict__ se, const float* __restrict__ lw, const float* __restrict__ lb,
    const float* __restrict__ W1, const float* __restrict__ b1,
    const float* __restrict__ W2, const float* __restrict__ b2,
    const float* __restrict__ nse, float* __restrict__ out_start)
{
  __shared__ float xs[H_], fx[H_], h1[H_];
  __shared__ float lg[C_];
  __shared__ float redk[4];
  int tid = threadIdx.x;
  xs[tid] = se[tid];
  __syncthreads();
  {
    float acc = lb[tid];
    const float4* wr = (const float4*)(lw + (size_t)tid*H_);
    for (int k = 0; k < H_/4; ++k) acc += dot4(wr[k], *(const float4*)&xs[k*4]);
    fx[tid] = acc;
  }
  __syncthreads();
  for (int L = 0; L < 2; ++L) {
    {
      float acc = b1[L*H_ + tid];
      const float4* wr = (const float4*)(W1 + (size_t)(L*H_ + tid)*H_);
      for (int k = 0; k < H_/4; ++k) acc += dot4(wr[k], *(const float4*)&fx[k*4]);
      h1[tid] = fmaxf(acc, 0.f);
    }
    __syncthreads();
    {
      float acc = b2[L*H_ + tid];
      const float4* wr = (const float4*)(W2 + (size_t)(L*H_ + tid)*H_);
      for (int k = 0; k < H_/4; ++k) acc += dot4(wr[k], *(const float4*)&h1[k*4]);
      fx[tid] += fmaxf(acc, 0.f);
    }
    __syncthreads();
  }
  float lmax = -1e30f;
  for (int r = 0; r < 4; ++r) {
    int cc = tid + r*256;
    float acc = 0.f;
    const float4* er = (const float4*)(nse + (size_t)cc*H_);
    for (int k = 0; k < H_/4; ++k) acc += dot4(er[k], *(const float4*)&fx[k*4]);
    lg[cc] = acc;
    lmax = fmaxf(lmax, acc);
  }
  for (int m = 32; m; m >>= 1) lmax = fmaxf(lmax, __shfl_xor(lmax, m, 64));
  if ((tid & 63) == 0) redk[tid >> 6] = lmax;
  __syncthreads();
  float M = fmaxf(fmaxf(redk[0], redk[1]), fmaxf(redk[2], redk[3]));
  __syncthreads();
  float ssum = 0.f;
  for (int r = 0; r < 4; ++r) ssum += __expf(lg[tid + r*256] - M);
  for (int m = 32; m; m >>= 1) ssum += __shfl_xor(ssum, m, 64);
  if ((tid & 63) == 0) redk[tid >> 6] = ssum;
  __syncthreads();
  float S = redk[0] + redk[1] + redk[2] + redk[3];
  float lse = M + __logf(S);
  for (int r = 0; r < 4; ++r) {
    int cc = tid + r*256;
    out_start[cc] = lg[cc] - lse;
  }
}

// ---------------------------------------------------------------- K2: transition logits GEMM (f32)
__global__ __launch_bounds__(256) void k_gemm_cc(
    const float* __restrict__ A, const float* __restrict__ B, float* __restrict__ Cout)
{
  __shared__ float As[64][69];
  __shared__ float Bs[64][69];
  int tid = threadIdx.x;
  int bi = blockIdx.y, bj = blockIdx.x;
  int sr = tid >> 2, sq = tid & 3;
  int tx = tid & 15, ty = tid >> 4;
  float acc[4][4] = {};
  for (int kb = 0; kb < H_; kb += 64) {
    __syncthreads();
    {
      const float* ar = A + (size_t)(bi*64 + sr)*H_ + kb + sq*16;
      const float* br = B + (size_t)(bj*64 + sr)*H_ + kb + sq*16;
#pragma unroll
      for (int qq = 0; qq < 4; ++qq) {
        float4 av = *(const float4*)(ar + qq*4);
        float4 bv = *(const float4*)(br + qq*4);
        int kk = sq*16 + qq*4;
        As[sr][kk+0]=av.x; As[sr][kk+1]=av.y; As[sr][kk+2]=av.z; As[sr][kk+3]=av.w;
        Bs[sr][kk+0]=bv.x; Bs[sr][kk+1]=bv.y; Bs[sr][kk+2]=bv.z; Bs[sr][kk+3]=bv.w;
      }
    }
    __syncthreads();
#pragma unroll 4
    for (int k = 0; k < 64; ++k) {
      float a0 = As[ty*4+0][k], a1 = As[ty*4+1][k], a2 = As[ty*4+2][k], a3 = As[ty*4+3][k];
      float b0 = Bs[tx*4+0][k], b1 = Bs[tx*4+1][k], b2 = Bs[tx*4+2][k], b3 = Bs[tx*4+3][k];
      acc[0][0]+=a0*b0; acc[0][1]+=a0*b1; acc[0][2]+=a0*b2; acc[0][3]+=a0*b3;
      acc[1][0]+=a1*b0; acc[1][1]+=a1*b1; acc[1][2]+=a1*b2; acc[1][3]+=a1*b3;
      acc[2][0]+=a2*b0; acc[2][1]+=a2*b1; acc[2][2]+=a2*b2; acc[2][3]+=a2*b3;
      acc[3][0]+=a3*b0; acc[3][1]+=a3*b1; acc[3][2]+=a3*b2; acc[3][3]+=a3*b3;
    }
  }
#pragma unroll
  for (int ii = 0; ii < 4; ++ii)
#pragma unroll
    for (int jj = 0; jj < 4; ++jj)
      Cout[(size_t)(bi*64 + ty*4 + ii)*C_ + bj*64 + tx*4 + jj] = acc[ii][jj];
}

// ---------------------------------------------------------------- K3: row softmax in place
__global__ __launch_bounds__(256) void k_softmax_rows(float* __restrict__ P)
{
  __shared__ float redk[4];
  int row = blockIdx.x, tid = threadIdx.x;
  float4* pr = (float4*)(P + (size_t)row*C_);
  float4 v = pr[tid];
  float m = fmaxf(fmaxf(v.x, v.y), fmaxf(v.z, v.w));
  for (int mm = 32; mm; mm >>= 1) m = fmaxf(m, __shfl_xor(m, mm, 64));
  if ((tid & 63) == 0) redk[tid >> 6] = m;
  __syncthreads();
  float M = fmaxf(fmaxf(redk[0], redk[1]), fmaxf(redk[2], redk[3]));
  __syncthreads();
  float4 e;
  e.x = __expf(v.x - M); e.y = __expf(v.y - M); e.z = __expf(v.z - M); e.w = __expf(v.w - M);
  float s = e.x + e.y + e.z + e.w;
  for (int mm = 32; mm; mm >>= 1) s += __shfl_xor(s, mm, 64);
  if ((tid & 63) == 0) redk[tid >> 6] = s;
  __syncthreads();
  float S = redk[0] + redk[1] + redk[2] + redk[3];
  float inv = 1.0f / S;
  e.x *= inv; e.y *= inv; e.z *= inv; e.w *= inv;
  pr[tid] = e;
}

// ---------------------------------------------------------------- K3b: pack P^T bf16 [j][m]
__global__ __launch_bounds__(256) void k_packT(
    const float* __restrict__ P, unsigned short* __restrict__ PT)
{
  __shared__ float ts[64][68];
  int tid = threadIdx.x;
  int bi = blockIdx.y, bj = blockIdx.x;
  int rl = tid >> 4;            // 0..15
  int cl4 = (tid & 15) * 4;
#pragma unroll
  for (int rr = 0; rr < 4; ++rr) {
    int row = rr*16 + rl;
    float4 v = *(const float4*)(P + (size_t)(bi*64 + row)*C_ + bj*64 + cl4);
    ts[row][cl4+0]=v.x; ts[row][cl4+1]=v.y; ts[row][cl4+2]=v.z; ts[row][cl4+3]=v.w;
  }
  __syncthreads();
  int jl = tid >> 2;            // 0..63
  int m0 = (tid & 3) * 16;
  unsigned pk[8];
#pragma unroll
  for (int u = 0; u < 8; ++u)
    pk[u] = pk_bf2(ts[m0 + u*2][jl], ts[m0 + u*2 + 1][jl]);
  char* dst = (char*)(PT + (size_t)(bj*64 + jl)*1024 + bi*64 + m0);
  *(uint4*)(dst +  0) = *(const uint4*)&pk[0];
  *(uint4*)(dst + 16) = *(const uint4*)&pk[4];
}

// ---------------------------------------------------------------- K4: terminal MLP
__global__ __launch_bounds__(256) void k_mlp(
    const float* __restrict__ inp, const float* __restrict__ W1, const float* __restrict__ b1,
    const float* __restrict__ W2, const float* __restrict__ b2, float* __restrict__ ft)
{
  __shared__ float xs[4][H_];
  __shared__ float hs[4][H_];
  int tid = threadIdx.x;
  int r0 = blockIdx.x * 4;
  int lr = tid >> 6, lc = (tid & 63) * 4;
  *(float4*)&xs[lr][lc] = *(const float4*)(inp + (size_t)(r0+lr)*H_ + lc);
  __syncthreads();
  for (int L = 0; L < 2; ++L) {
    {
      const float4* wr = (const float4*)(W1 + (size_t)(L*H_ + tid)*H_);
      float bb = b1[L*H_ + tid];
      float a0=bb, a1=bb, a2=bb, a3=bb;
      for (int k = 0; k < H_/4; ++k) {
        float4 w = wr[k];
        a0 += dot4(w, *(const float4*)&xs[0][k*4]);
        a1 += dot4(w, *(const float4*)&xs[1][k*4]);
        a2 += dot4(w, *(const float4*)&xs[2][k*4]);
        a3 += dot4(w, *(const float4*)&xs[3][k*4]);
      }
      hs[0][tid]=fmaxf(a0,0.f); hs[1][tid]=fmaxf(a1,0.f);
      hs[2][tid]=fmaxf(a2,0.f); hs[3][tid]=fmaxf(a3,0.f);
    }
    __syncthreads();
    {
      const float4* wr = (const float4*)(W2 + (size_t)(L*H_ + tid)*H_);
      float bb = b2[L*H_ + tid];
      float a0=bb, a1=bb, a2=bb, a3=bb;
      for (int k = 0; k < H_/4; ++k) {
        float4 w = wr[k];
        a0 += dot4(w, *(const float4*)&hs[0][k*4]);
        a1 += dot4(w, *(const float4*)&hs[1][k*4]);
        a2 += dot4(w, *(const float4*)&hs[2][k*4]);
        a3 += dot4(w, *(const float4*)&hs[3][k*4]);
      }
      xs[0][tid] += fmaxf(a0,0.f); xs[1][tid] += fmaxf(a1,0.f);
      xs[2][tid] += fmaxf(a2,0.f); xs[3][tid] += fmaxf(a3,0.f);
    }
    __syncthreads();
  }
  *(float4*)(ft + (size_t)(r0+lr)*H_ + lc) = *(float4*)&xs[lr][lc];
}

// ---------------------------------------------------------------- K5: emission LSE via MFMA
#define LSE_VSPLIT 16
#define LSE_VPB    2000
#define LSE_CHUNKS 125

__global__ __launch_bounds__(256) void k_lse_mfma(
    const float* __restrict__ ft, const float* __restrict__ emb, float* __restrict__ part)
{
  int tid = threadIdx.x;
  int lane = tid & 63;
  int w = tid >> 6;
  int q = blockIdx.x;
  int jb = blockIdx.y * 64 + w * 16;
  int r16 = lane & 15, kb = lane >> 4;

  short8 A[8];
  {
    const float* arow = ft + (size_t)(jb + r16) * H_ + kb * 8;
#pragma unroll
    for (int ks = 0; ks < 8; ++ks) {
      float4 a = *(const float4*)(arow + ks * 32);
      float4 b = *(const float4*)(arow + ks * 32 + 4);
      A[ks] = pack8(a, b);
    }
  }
  float s0 = 0.f, s1 = 0.f, s2 = 0.f, s3 = 0.f;
  const float* embq = emb + (size_t)q * LSE_VPB * H_;
#pragma unroll 1
  for (int ch = 0; ch < LSE_CHUNKS; ++ch) {
    const float* brow = embq + (size_t)(ch * 16 + r16) * H_ + kb * 8;
    floatx4 acca = {0,0,0,0}, accb = {0,0,0,0};
#pragma unroll
    for (int ks = 0; ks < 8; ks += 2) {
      float4 x0 = *(const float4*)(brow + ks * 32);
      float4 y0 = *(const float4*)(brow + ks * 32 + 4);
      float4 x1 = *(const float4*)(brow + ks * 32 + 32);
      float4 y1 = *(const float4*)(brow + ks * 32 + 36);
      acca = __builtin_amdgcn_mfma_f32_16x16x32_bf16(A[ks],   pack8(x0, y0), acca, 0, 0, 0);
      accb = __builtin_amdgcn_mfma_f32_16x16x32_bf16(A[ks+1], pack8(x1, y1), accb, 0, 0, 0);
    }
    s0 += __expf(acca[0] + accb[0]);
    s1 += __expf(acca[1] + accb[1]);
    s2 += __expf(acca[2] + accb[2]);
    s3 += __expf(acca[3] + accb[3]);
  }
#pragma unroll
  for (int mm = 1; mm <= 8; mm <<= 1) {
    s0 += __shfl_xor(s0, mm, 64);
    s1 += __shfl_xor(s1, mm, 64);
    s2 += __shfl_xor(s2, mm, 64);
    s3 += __shfl_xor(s3, mm, 64);
  }
  if (r16 == 0) {
    int jrow = jb + kb * 4;
    part[(size_t)(jrow + 0) * LSE_VSPLIT + q] = s0;
    part[(size_t)(jrow + 1) * LSE_VSPLIT + q] = s1;
    part[(size_t)(jrow + 2) * LSE_VSPLIT + q] = s2;
    part[(size_t)(jrow + 3) * LSE_VSPLIT + q] = s3;
  }
}

// ---------------------------------------------------------------- K6: combine LSE partials
__global__ __launch_bounds__(256) void k_lse_reduce(
    const float* __restrict__ part, float* __restrict__ lse_row)
{
  int row = blockIdx.x * 256 + threadIdx.x;
  const float4* p = (const float4*)(part + (size_t)row * LSE_VSPLIT);
  float4 a = p[0], b = p[1], c = p[2], d = p[3];
  float s = a.x+a.y+a.z+a.w + b.x+b.y+b.z+b.w + c.x+c.y+c.z+c.w + d.x+d.y+d.z+d.w;
  lse_row[row] = __logf(s);
}

// ---------------------------------------------------------------- K7: EEXP via MFMA (gathered B)
__global__ __launch_bounds__(256) void k_eexp_mfma(
    const float* __restrict__ ft, const float* __restrict__ emb, const int* __restrict__ text,
    const float* __restrict__ lse_row, float* __restrict__ EEXP)
{
  int tid = threadIdx.x;
  int lane = tid & 63;
  int w = tid >> 6;
  int jb = blockIdx.y * 64 + w * 16;
  int tb = blockIdx.x * 64;
  int r16 = lane & 15, kb = lane >> 4;

  short8 A[8];
  {
    const float* arow = ft + (size_t)(jb + r16) * H_ + kb * 8;
#pragma unroll
    for (int ks = 0; ks < 8; ++ks) {
      float4 a = *(const float4*)(arow + ks * 32);
      float4 b = *(const float4*)(arow + ks * 32 + 4);
      A[ks] = pack8(a, b);
    }
  }
  float4 lsej = *(const float4*)(lse_row + jb + kb * 4);

#pragma unroll 1
  for (int tc = 0; tc < 4; ++tc) {
    int idx = tb + tc * 16 + r16;
    int tok = text[idx];
    const float* brow = emb + (size_t)tok * H_ + kb * 8;
    floatx4 acca = {0,0,0,0}, accb = {0,0,0,0};
#pragma unroll
    for (int ks = 0; ks < 8; ks += 2) {
      float4 x0 = *(const float4*)(brow + ks * 32);
      float4 y0 = *(const float4*)(brow + ks * 32 + 4);
      float4 x1 = *(const float4*)(brow + ks * 32 + 32);
      float4 y1 = *(const float4*)(brow + ks * 32 + 36);
      acca = __builtin_amdgcn_mfma_f32_16x16x32_bf16(A[ks],   pack8(x0, y0), acca, 0, 0, 0);
      accb = __builtin_amdgcn_mfma_f32_16x16x32_bf16(A[ks+1], pack8(x1, y1), accb, 0, 0, 0);
    }
    float4 o;
    o.x = __expf(acca[0] + accb[0] - lsej.x);
    o.y = __expf(acca[1] + accb[1] - lsej.y);
    o.z = __expf(acca[2] + accb[2] - lsej.z);
    o.w = __expf(acca[3] + accb[3] - lsej.w);
    *(float4*)(EEXP + (size_t)idx * C_ + jb + kb * 4) = o;
  }
}

// ---------------------------------------------------------------- K8: persistent scan, double-step, lean rounds
// 64 WGs = 16 chunks x 4 groups (c = bid>>2, ng = bid&3). WG owns 64 cols/rows.
// Round r: [hoisted EEXP loads] -> poll cnt>=16r -> read sums buf[(r-1)%3] ->
// apply e_{2r}, pack alpha^ (LAGGED rescale Muse) -> B -> u (per-wave col-tile,
// full K, 4 acc chains) *e_{2r+1} -> Ub -> B -> v (A=Ub, B=preloaded P^T regs),
// atomic-add scatter into buf[r%3] -> B(drain) -> cnt++.
// Monotonic counter per group (no flag resets). v B-frags loaded ONCE from PT.
// LDS: Pl 128KB [col64][m1024] bf16 swz((col&15)<<4); Al 4KB; Ub 256B; redm 32B.
#define SCAN_LDS (131072 + 4096 + 256 + 32)

__global__ __launch_bounds__(256) void k_scan(
    const unsigned short* __restrict__ PT, const float* __restrict__ EEXP,
    const float* __restrict__ startv,
    float* __restrict__ bufG, unsigned* __restrict__ cntG, float* __restrict__ evp)
{
  extern __shared__ char smem[];
  char*  Pl   = smem;                      // 131072
  char*  Al   = smem + 131072;             // 4096
  char*  Ub   = smem + 135168;             // 256
  float* redm = (float*)(smem + 135424);   // 32

  int tid  = threadIdx.x;
  int bid  = blockIdx.x;
  int c    = bid >> 2;          // chunk 0..15 (64 cols/rows)
  int ng   = bid & 3;           // group 0..3
  int n0   = ng * 2;
  int lane = tid & 63;
  int w    = tid >> 6;          // wave 0..3 = u col-tile / v j-quarter
  int s    = tid >> 7;          // consumer seq 0/1
  int k0   = (tid & 127) * 8;   // consumer m/j base
  int r16  = lane & 15;
  int kb4  = lane >> 4;         // 0..3

  unsigned* cnt = cntG + ng * 16;   // padded to 64B apart
  float* bufq[3];
  bufq[0] = bufG + (size_t)(0*4 + ng)*2048;
  bufq[1] = bufG + (size_t)(1*4 + ng)*2048;
  bufq[2] = bufG + (size_t)(2*4 + ng)*2048;

  // ---- stage Pl from PT rows [c*64, +64): Pl[col][m] byte = col*2048 + (2m ^ ((col&15)<<4))
  {
    int col = tid & 63, q = tid >> 6;
    const char* src = (const char*)(PT + (size_t)(c*64 + col)*1024) + q*512;
    char* dstb = Pl + (size_t)col*2048;
    int swz = (col & 15) << 4;
#pragma unroll
    for (int u = 0; u < 32; ++u)
      *(uint4*)(dstb + ((q*512 + u*16) ^ swz)) = *(const uint4*)(src + u*16);
  }

  // ---- preload v B-fragments from PT (constant across rounds): jt = w*16+i
  short8 vb[16][2];
#pragma unroll
  for (int i = 0; i < 16; ++i)
#pragma unroll
    for (int q = 0; q < 2; ++q)
      vb[i][q] = *(const short8*)((const char*)PT +
          ((size_t)((w*16 + i)*16 + r16)*1024 + c*64 + q*32 + kb4*8)*2);

  __syncthreads();

  float ls   = 0.f;
  float Muse = 1.f;
  int s2   = r16 & 1;
  int ucol = c*64 + w*16 + r16;

#pragma unroll 1
  for (int r = 0; r < 256; ++r) {
    // ---- hoisted round-constant loads (complete during poll)
    float ue0 = 0.f, ue1 = 0.f;
    if (lane < 16) {
      ue0 = EEXP[((size_t)(n0+0)*T_ + (2*r+1))*C_ + ucol];
      ue1 = EEXP[((size_t)(n0+1)*T_ + (2*r+1))*C_ + ucol];
    }
    float4 e0 = *(const float4*)(EEXP + ((size_t)(n0+s)*T_ + 2*r)*C_ + k0);
    float4 e1 = *(const float4*)(EEXP + ((size_t)(n0+s)*T_ + 2*r)*C_ + k0 + 4);

    float av[8];
    if (r == 0) {
      av[0] = __expf(startv[k0+0]) * e0.x;
      av[1] = __expf(startv[k0+1]) * e0.y;
      av[2] = __expf(startv[k0+2]) * e0.z;
      av[3] = __expf(startv[k0+3]) * e0.w;
      av[4] = __expf(startv[k0+4]) * e1.x;
      av[5] = __expf(startv[k0+5]) * e1.y;
      av[6] = __expf(startv[k0+6]) * e1.z;
      av[7] = __expf(startv[k0+7]) * e1.w;
    } else {
      // ---- poll monotonic counter
      unsigned tgt = 16u * (unsigned)r;
      int guard = 0;
      for (;;) {
        unsigned f = __hip_atomic_load(cnt, __ATOMIC_RELAXED, __HIP_MEMORY_SCOPE_AGENT);
        if (f >= tgt) break;
        __builtin_amdgcn_s_sleep(1);
        if (++guard > 4000000) break;
      }
      // ---- read sums, apply e_{2r}
      float* srcb = bufq[(r-1)%3] + s*1024 + k0;
      float sv[8];
#pragma unroll
      for (int j = 0; j < 8; ++j)
        sv[j] = __hip_atomic_load(srcb + j, __ATOMIC_RELAXED, __HIP_MEMORY_SCOPE_AGENT);
      av[0]=sv[0]*e0.x; av[1]=sv[1]*e0.y; av[2]=sv[2]*e0.z; av[3]=sv[3]*e0.w;
      av[4]=sv[4]*e1.x; av[5]=sv[5]*e1.y; av[6]=sv[6]*e1.z; av[7]=sv[7]*e1.w;
      // ---- reset own slice of buf[(r+1)%3] (certified idle by cnt>=16r)
      if (tid < 128) {
        int ss = tid >> 6, col = c*64 + (tid & 63);
        __hip_atomic_store(bufq[(r+1)%3] + ss*1024 + col, 0.0f,
                           __ATOMIC_RELAXED, __HIP_MEMORY_SCOPE_AGENT);
      }
    }

    // ---- lagged rescale: apply 1/Muse (from prev round); compute this round's max off-path
    ls += __logf(Muse);
    float rinv = 1.0f / Muse;
    float m8 = fmaxf(fmaxf(fmaxf(av[0],av[1]),fmaxf(av[2],av[3])),
                     fmaxf(fmaxf(av[4],av[5]),fmaxf(av[6],av[7])));
#pragma unroll
    for (int mm = 1; mm <= 32; mm <<= 1) m8 = fmaxf(m8, __shfl_xor(m8, mm, 64));
    if (lane == 0) redm[w] = m8;
    {
      unsigned pk[4];
      pk[0] = pk_bf2(av[0]*rinv, av[1]*rinv);
      pk[1] = pk_bf2(av[2]*rinv, av[3]*rinv);
      pk[2] = pk_bf2(av[4]*rinv, av[5]*rinv);
      pk[3] = pk_bf2(av[6]*rinv, av[7]*rinv);
      int blk = k0 >> 5;
      *(uint4*)(Al + blk*128 + s*64 + (((k0&31)*2) ^ ((blk&3)<<4))) = *(const uint4*)pk;
    }
    __syncthreads();                                        // B2: Al + redm ready
    Muse = fmaxf(fmaxf(redm[0], redm[1]), fmaxf(redm[2], redm[3])) * rinv;

    // ---- u-matvec: wave w -> col-tile w (16 cols), full K, 4 acc chains
    floatx4 acc[4] = {{0,0,0,0},{0,0,0,0},{0,0,0,0},{0,0,0,0}};
    {
      const char* bcol = Pl + (size_t)(w*16 + r16)*2048;
      int swzc = r16 << 4;
#pragma unroll
      for (int ch = 0; ch < 4; ++ch)
#pragma unroll
        for (int b8 = 0; b8 < 8; ++b8) {
          int blk = b8*4 + ch;
          short8 af = *(const short8*)(Al + blk*128 + s2*64 + ((kb4*16) ^ ((blk&3)<<4)));
          short8 bf = *(const short8*)(bcol + ((blk*64 + kb4*16) ^ swzc));
          acc[ch] = __builtin_amdgcn_mfma_f32_16x16x32_bf16(af, bf, acc[ch], 0, 0, 0);
        }
    }
    floatx4 us;
    us[0] = (acc[0][0]+acc[1][0]) + (acc[2][0]+acc[3][0]);
    us[1] = (acc[0][1]+acc[1][1]) + (acc[2][1]+acc[3][1]);

    if (r == 255) {
      // ---- final single step: add u (f32) directly into buf[0] (= bufq[255%3])
      if (lane < 16) {
        (void)__hip_atomic_fetch_add(bufq[0] + 0*1024 + ucol, us[0]*ue0,
                                     __ATOMIC_RELAXED, __HIP_MEMORY_SCOPE_AGENT);
        (void)__hip_atomic_fetch_add(bufq[0] + 1*1024 + ucol, us[1]*ue1,
                                     __ATOMIC_RELAXED, __HIP_MEMORY_SCOPE_AGENT);
      }
      __syncthreads();                                      // drain
      if (tid == 0)
        (void)__hip_atomic_fetch_add(cnt, 1u, __ATOMIC_RELAXED, __HIP_MEMORY_SCOPE_AGENT);
    } else {
      // ---- finalize u, apply e_{2r+1}, pack to Ub
      if (lane < 16) {
        *(unsigned short*)(Ub + 0*128 + (w*16 + r16)*2) = f2bf(us[0] * ue0);
        *(unsigned short*)(Ub + 1*128 + (w*16 + r16)*2) = f2bf(us[1] * ue1);
      }
      __syncthreads();                                      // B4: Ub ready
      // ---- v-matvec: A from Ub, B preloaded; scatter-reduce atomic adds
      short8 ua0 = *(const short8*)(Ub + s2*128 +  0 + kb4*16);
      short8 ua1 = *(const short8*)(Ub + s2*128 + 64 + kb4*16);
      float* bufp = bufq[r%3];
#pragma unroll
      for (int i = 0; i < 16; ++i) {
        floatx4 a = {0,0,0,0};
        a = __builtin_amdgcn_mfma_f32_16x16x32_bf16(ua0, vb[i][0], a, 0, 0, 0);
        a = __builtin_amdgcn_mfma_f32_16x16x32_bf16(ua1, vb[i][1], a, 0, 0, 0);
        if (lane < 16) {
          int jc = (w*16 + i)*16 + r16;
          (void)__hip_atomic_fetch_add(bufp + jc, a[0],
                                       __ATOMIC_RELAXED, __HIP_MEMORY_SCOPE_AGENT);
          (void)__hip_atomic_fetch_add(bufp + 1024 + jc, a[1],
                                       __ATOMIC_RELAXED, __HIP_MEMORY_SCOPE_AGENT);
        }
      }
      __syncthreads();                                      // B5: drains all adds
      if (tid == 0)
        (void)__hip_atomic_fetch_add(cnt, 1u, __ATOMIC_RELAXED, __HIP_MEMORY_SCOPE_AGENT);
    }
  }

  // ---- tail: chunk-0 WG per group: logsumexp of alpha_511
  if (c == 0) {
    int guard = 0;
    for (;;) {
      unsigned f = __hip_atomic_load(cnt, __ATOMIC_RELAXED, __HIP_MEMORY_SCOPE_AGENT);
      if (f >= 4096u) break;
      __builtin_amdgcn_s_sleep(1);
      if (++guard > 4000000) break;
    }
    float* srcb = bufq[0] + s*1024 + k0;
    float ssum = 0.f;
#pragma unroll
    for (int j = 0; j < 8; ++j)
      ssum += __hip_atomic_load(srcb + j, __ATOMIC_RELAXED, __HIP_MEMORY_SCOPE_AGENT);
#pragma unroll
    for (int mm = 1; mm <= 32; mm <<= 1) ssum += __shfl_xor(ssum, mm, 64);
    if (lane == 0) redm[w] = ssum;
    __syncthreads();
    if (tid == 0)   evp[n0]     = ls + __logf(redm[0] + redm[1]);
    if (tid == 128) evp[n0 + 1] = ls + __logf(redm[2] + redm[3]);
  }
}

// ---------------------------------------------------------------- K9: final sum
__global__ void k_final(const float* __restrict__ evp, float* __restrict__ out)
{
  if (threadIdx.x == 0) {
    float s = 0.f;
#pragma unroll
    for (int i = 0; i < N_; ++i) s += evp[i];
    out[0] = s;
  }
}

// ----------------------------------------------------------------
extern "C" void kernel_launch(void* const* d_in, const int* in_sizes, int n_in,
                              void* d_out, int out_size, void* d_ws, size_t ws_size,
                              hipStream_t stream)
{
  const int*   text      = (const int*)  d_in[0];
  const float* start_emb = (const float*)d_in[1];
  const float* slw       = (const float*)d_in[2];
  const float* slb       = (const float*)d_in[3];
  const float* sW1       = (const float*)d_in[4];
  const float* sb1       = (const float*)d_in[5];
  const float* sW2       = (const float*)d_in[6];
  const float* sb2       = (const float*)d_in[7];
  const float* state_emb = (const float*)d_in[8];
  const float* nse       = (const float*)d_in[9];
  const float* pre_emb   = (const float*)d_in[10];
  const float* tW1       = (const float*)d_in[11];
  const float* tb1       = (const float*)d_in[12];
  const float* tW2       = (const float*)d_in[13];
  const float* tb2       = (const float*)d_in[14];
  const float* term_emb  = (const float*)d_in[15];

  char* ws = (char*)d_ws;
  float*          w_start = (float*)         (ws + OFF_START);
  float*          w_lse   = (float*)         (ws + OFF_LSE);
  float*          w_evp   = (float*)         (ws + OFF_EVP);
  float*          w_ft    = (float*)         (ws + OFF_FT);
  float*          w_P     = (float*)         (ws + OFF_P);
  float*          w_part  = (float*)         (ws + OFF_PART);
  float*          w_eexp  = (float*)         (ws + OFF_EEXP);
  float*          w_buf   = (float*)         (ws + OFF_BUF);
  unsigned*       w_cnt   = (unsigned*)      (ws + OFF_CNT);
  unsigned short* w_pt    = (unsigned short*)(ws + OFF_PT);

  // zero sum buffers + counters
  (void)hipMemsetAsync(ws + OFF_BUF, 0, 98304 + 512, stream);

  k_start<<<1, 256, 0, stream>>>(start_emb, slw, slb, sW1, sb1, sW2, sb2, nse, w_start);
  k_gemm_cc<<<dim3(16,16), 256, 0, stream>>>(state_emb, nse, w_P);
  k_softmax_rows<<<C_, 256, 0, stream>>>(w_P);
  k_packT<<<dim3(16,16), 256, 0, stream>>>(w_P, w_pt);
  k_mlp<<<C_/4, 256, 0, stream>>>(pre_emb, tW1, tb1, tW2, tb2, w_ft);
  k_lse_mfma<<<dim3(LSE_VSPLIT, 16), 256, 0, stream>>>(w_ft, term_emb, w_part);
  k_lse_reduce<<<4, 256, 0, stream>>>(w_part, w_lse);
  k_eexp_mfma<<<dim3(64, 16), 256, 0, stream>>>(w_ft, term_emb, text, w_lse, w_eexp);

  (void)hipFuncSetAttribute((const void*)k_scan, hipFuncAttributeMaxDynamicSharedMemorySize, SCAN_LDS);
  k_scan<<<64, 256, SCAN_LDS, stream>>>(w_pt, w_eexp, w_start, w_buf, w_cnt, w_evp);
  k_final<<<1, 64, 0, stream>>>(w_evp, (float*)d_out);
}